// Round 8
// baseline (8393.071 us; speedup 1.0000x reference)
//
#include <hip/hip_runtime.h>
#include <hip/hip_bf16.h>

// ---------------------------------------------------------------------------
// 3-layer original-paper GRU, B=128, T=128, I=512, H={512,1024,2048}.
// Round 13: R12 schedule + retile N=64/BK=64 for fewer staged bytes and
// higher co-residency.
//  - R12 (N=32,M=64,BK=128, 3 blk/CU): 6862us, tick 52us. Model: staged
//    293MB/tick at ~9.2TB/s aggregate + l2-block tail 384KB.
//  - This round: N=64, M=64, BK=64, 256 thr (4 waves, 32x32 each),
//    LDS 2x(8+8)KB = 32KB -> 4-5 blocks/CU. Staged bytes 12->8 NgK
//    (195MB/tick, -33%); BK=64 extra barriers hidden by co-residency
//    (R8's BK=64 failure was at 1 blk/CU).
//  - Schedule/roles/numerics byte-identical to R12 otherwise: tick u =
//    layer l at t=u-2l; zr launch = zr-gates + gi1; n launch = n-gates +
//    gi2; mh row-halves paired same-XCD (split at multiple of 8);
//    coherence via kernel boundaries only.
// ---------------------------------------------------------------------------

typedef __attribute__((ext_vector_type(8))) short s16x8;
typedef __attribute__((ext_vector_type(4))) float f32x4;

#define LLDS16(g, s)                                                          \
  __builtin_amdgcn_global_load_lds(                                           \
      (const __attribute__((address_space(1))) void*)(g),                     \
      (__attribute__((address_space(3))) void*)(s), 16, 0, 0)

__device__ __forceinline__ unsigned short f2b(float f) {
  unsigned int u = __float_as_uint(f);
  unsigned int r = (u + 0x7FFFu + ((u >> 16) & 1u)) >> 16;
  return (unsigned short)r;
}
__device__ __forceinline__ float sigmoidf_(float x) {
  return 1.0f / (1.0f + __expf(-x));
}
__device__ __forceinline__ float tanhf_(float x) {
  x = fminf(fmaxf(x, -15.0f), 15.0f);
  float e = __expf(-2.0f * x);
  return (1.0f - e) / (1.0f + e);
}

struct DiagP {
  const unsigned short* xb;            // [B,T,I] bf16
  const unsigned short* wihzr0;        // [2*512, 512]
  const unsigned short* wihn0;         // [512, 512]
  const unsigned short* wihF[3];       // full [3H, inl] (l=1,2 used)
  const unsigned short* whhzr[3];      // [2H, H]
  const unsigned short* whhn[3];       // [H, H]
  const float* bias[3];                // [3H]
  float* hf[3][2];                     // f32 h, 2 slots (tick parity)
  unsigned short* hb[3][2];            // bf16 h, 2 slots
  float* zb[3];                        // [B,H] f32
  unsigned short* rh[3];               // [B,H] bf16
  float* gi[3][2];                     // [B,3H] f32, 2 slots (t parity)
  const float* mask;                   // [B,T]
  float* out;                          // [B,3584]
};

// ---- staging (256 thr): 64-row x 64-col bf16 tile (8KB) per call ----------
// LDS row r at r*128B (8 granules of 16B); slot s holds source col-group
// s^(r&7) -- XOR swizzle via pre-swizzled global source (reader matches).
__device__ __forceinline__ void stage64(const unsigned short* __restrict__ g,
                                        size_t ld, int rowbase, int k0,
                                        unsigned short* lds) {
  const int tid = threadIdx.x;
#pragma unroll
  for (int j = 0; j < 2; ++j) {
    int idx = j * 256 + tid;          // 0..511 granules
    int r = idx >> 3;                 // 0..63
    int cg = (idx & 7) ^ (r & 7);
    LLDS16(g + (size_t)(rowbase + r) * ld + k0 + cg * 8, lds + idx * 8);
  }
}

// ---- one BK=64 chunk: wave (wr=wave>>1, wc=wave&1) computes rows
// wr*32+[0,32), cols wc*32+[0,32): 8 ds_read_b128 + 8 MFMA per wave.
__device__ __forceinline__ void cchunk(const unsigned short* Ab,
                                       const unsigned short* Bb,
                                       f32x4 acc[2][2]) {
  const int tid = threadIdx.x;
  const int wave = tid >> 6, lane = tid & 63;
  const int wr = wave >> 1, wc = wave & 1, quad = lane >> 4, l16 = lane & 15;
#pragma unroll
  for (int ks = 0; ks < 2; ++ks) {
    int kg = ks * 4 + quad;           // 0..7
    s16x8 bv[2], av[2];
#pragma unroll
    for (int ni = 0; ni < 2; ++ni) {
      int br = wc * 32 + ni * 16 + l16;
      bv[ni] = *(const s16x8*)(Bb + (size_t)br * 64 + ((kg ^ (br & 7)) * 8));
    }
#pragma unroll
    for (int mi = 0; mi < 2; ++mi) {
      int ar = wr * 32 + mi * 16 + l16;
      av[mi] = *(const s16x8*)(Ab + (size_t)ar * 64 + ((kg ^ (ar & 7)) * 8));
    }
#pragma unroll
    for (int mi = 0; mi < 2; ++mi)
#pragma unroll
      for (int ni = 0; ni < 2; ++ni)
        acc[mi][ni] = __builtin_amdgcn_mfma_f32_16x16x32_bf16(
            av[mi], bv[ni], acc[mi][ni], 0, 0, 0);
  }
}

// acc += A1@B1^T (c1 BK=64 chunks) + A2@B2^T (c2 chunks); B rows at rowbase.
// Proven 2-buffer engine: per-chunk __syncthreads drain; exposed latency is
// hidden by the 3-4 other co-resident blocks on the CU.
__device__ __forceinline__ void gemm_diag(
    const unsigned short* __restrict__ A1, size_t ldA1, int c1,
    const unsigned short* __restrict__ A2, size_t ldA2, int c2,
    const unsigned short* __restrict__ B1, size_t ldB1,
    const unsigned short* __restrict__ B2, size_t ldB2, int rowbase,
    unsigned short* As, unsigned short* Bs, f32x4 acc[2][2]) {
  const int total = c1 + c2;
  auto issue = [&](int c, int buf) {
    unsigned short* a = As + buf * 4096;
    unsigned short* b = Bs + buf * 4096;
    if (c < c1) {
      stage64(A1, ldA1, 0, c << 6, a);
      stage64(B1, ldB1, rowbase, c << 6, b);
    } else {
      int k0 = (c - c1) << 6;
      stage64(A2, ldA2, 0, k0, a);
      stage64(B2, ldB2, rowbase, k0, b);
    }
  };
  issue(0, 0);
#pragma unroll 1
  for (int c = 0; c < total; ++c) {
    __syncthreads();  // drains vmcnt: chunk c resident; WAR-protects buffers
    if (c + 1 < total) issue(c + 1, (c + 1) & 1);
    cchunk(As + (c & 1) * 4096, Bs + (c & 1) * 4096, acc);
  }
}

// ---- zr launch: zr-gates + gi1. Grid 320 = 2*(112+48). -------------------
// role<112: zr(l,nt): l0 nt 0..15, l1 0..31, l2 0..63. role>=112: gi1 g.
__global__ __launch_bounds__(256) void diag_zr(DiagP p, int u) {
  __shared__ unsigned short As[2 * 4096], Bs[2 * 4096];
  const int blk = blockIdx.x;
  const int mh = (blk >= 160) ? 1 : 0;
  const int role = blk - 160 * mh;
  const int tid = threadIdx.x, wave = tid >> 6, lane = tid & 63;
  const int wr = wave >> 1, wc = wave & 1, quad = lane >> 4, l16 = lane & 15;
  const int oldS = (u + 1) & 1;

  if (role < 112) {
    const int l = (role < 16) ? 0 : ((role < 48) ? 1 : 2);
    const int nt = role - ((l == 0) ? 0 : ((l == 1) ? 16 : 48));
    const int t = u - 2 * l;
    if (t < 0 || t >= 128) return;
    const int H = 512 << l;

    f32x4 acc[2][2] = {};
    if (l == 0) {
      gemm_diag(p.xb + (size_t)t * 512 + (size_t)mh * 64 * 65536, 65536, 8,
                p.hb[0][oldS] + (size_t)mh * 64 * 512, 512, 8, p.wihzr0, 512,
                p.whhzr[0], 512, nt * 64, As, Bs, acc);
    } else {
      gemm_diag(p.hb[l][oldS] + (size_t)mh * 64 * H, (size_t)H, H >> 6,
                (const unsigned short*)0, 0, 0, p.whhzr[l], (size_t)H,
                (const unsigned short*)0, 0, nt * 64, As, Bs, acc);
    }

    const float* hfo = p.hf[l][oldS];
    const float* gil = (l == 0) ? (const float*)0 : p.gi[l][t & 1];
#pragma unroll
    for (int ni = 0; ni < 2; ++ni) {
      const int colg = nt * 64 + wc * 32 + ni * 16 + l16;
      const float bv = p.bias[l][colg];
      const bool isz = colg < H;  // uniform per block (64 | H)
      const int j = isz ? colg : colg - H;
#pragma unroll
      for (int mi = 0; mi < 2; ++mi)
#pragma unroll
        for (int r = 0; r < 4; ++r) {
          const int row = mh * 64 + wr * 32 + mi * 16 + quad * 4 + r;
          float v = acc[mi][ni][r] + bv;
          if (l) v += gil[(size_t)row * 3 * H + colg];
          float s = sigmoidf_(v);
          if (isz)
            p.zb[l][(size_t)row * H + j] = s;
          else
            p.rh[l][(size_t)row * H + j] = f2b(s * hfo[(size_t)row * H + j]);
        }
    }
  } else {
    // gi1: gi(1, tg=u-1) = h0(tg) @ WihF[1]^T (raw). Consumed zr(1,tg) @u+1.
    const int g = role - 112;  // 0..47
    const int tg = u - 1;
    if (tg < 0 || tg >= 128) return;
    f32x4 acc[2][2] = {};
    gemm_diag(p.hb[0][oldS] + (size_t)mh * 64 * 512, 512, 8,
              (const unsigned short*)0, 0, 0, p.wihF[1], 512,
              (const unsigned short*)0, 0, g * 64, As, Bs, acc);
    float* gd = p.gi[1][tg & 1];
#pragma unroll
    for (int ni = 0; ni < 2; ++ni)
#pragma unroll
      for (int mi = 0; mi < 2; ++mi)
#pragma unroll
        for (int rr = 0; rr < 4; ++rr) {
          int row = mh * 64 + wr * 32 + mi * 16 + quad * 4 + rr;
          int colg = g * 64 + wc * 32 + ni * 16 + l16;
          gd[(size_t)row * 3072 + colg] = acc[mi][ni][rr];
        }
  }
}

// ---- n launch: n-gates + gi2. Grid 304 = 2*(56+96). ----------------------
__global__ __launch_bounds__(256) void diag_n(DiagP p, int u) {
  __shared__ unsigned short As[2 * 4096], Bs[2 * 4096];
  const int blk = blockIdx.x;
  const int mh = (blk >= 152) ? 1 : 0;
  const int role = blk - 152 * mh;
  const int tid = threadIdx.x, wave = tid >> 6, lane = tid & 63;
  const int wr = wave >> 1, wc = wave & 1, quad = lane >> 4, l16 = lane & 15;
  const int oldS = (u + 1) & 1, newS = u & 1;

  if (role < 56) {
    const int l = (role < 8) ? 0 : ((role < 24) ? 1 : 2);
    const int nt = role - ((l == 0) ? 0 : ((l == 1) ? 8 : 24));
    const int t = u - 2 * l;
    if (t < 0 || t >= 128) return;
    const int H = 512 << l;
    const int outoff = (l == 0) ? 0 : ((l == 1) ? 512 : 1536);

    f32x4 acc[2][2] = {};
    if (l == 0) {
      gemm_diag(p.xb + (size_t)t * 512 + (size_t)mh * 64 * 65536, 65536, 8,
                p.rh[0] + (size_t)mh * 64 * 512, 512, 8, p.wihn0, 512,
                p.whhn[0], 512, nt * 64, As, Bs, acc);
    } else {
      gemm_diag(p.rh[l] + (size_t)mh * 64 * H, (size_t)H, H >> 6,
                (const unsigned short*)0, 0, 0, p.whhn[l], (size_t)H,
                (const unsigned short*)0, 0, nt * 64, As, Bs, acc);
    }

    const float* hfo = p.hf[l][oldS];
    float* hfn = p.hf[l][newS];
    unsigned short* hbn = p.hb[l][newS];
    const float* gil =
        (l == 0) ? (const float*)0 : (p.gi[l][t & 1] + 2 * H);  // n chunk
#pragma unroll
    for (int ni = 0; ni < 2; ++ni) {
      const int colg = nt * 64 + wc * 32 + ni * 16 + l16;
      const float bv = p.bias[l][2 * H + colg];
#pragma unroll
      for (int mi = 0; mi < 2; ++mi)
#pragma unroll
        for (int r = 0; r < 4; ++r) {
          const int row = mh * 64 + wr * 32 + mi * 16 + quad * 4 + r;
          float v = acc[mi][ni][r] + bv;
          if (l) v += gil[(size_t)row * 3 * H + colg];
          float nv = tanhf_(v);
          size_t idx = (size_t)row * H + colg;
          float z = p.zb[l][idx];
          float hn = (1.0f - z) * nv + z * hfo[idx];
          hfn[idx] = hn;
          hbn[idx] = f2b(hn);
          p.out[(size_t)row * 3584 + outoff + colg] +=
              p.mask[row * 128 + t] * hn;
        }
    }
  } else {
    // gi2: gi(2, tg=u-3) = h1(tg) @ WihF[2]^T (raw). Consumed zr(2,tg) @u+1.
    const int g = role - 56;  // 0..95
    const int tg = u - 3;
    if (tg < 0 || tg >= 128) return;
    f32x4 acc[2][2] = {};
    gemm_diag(p.hb[1][oldS] + (size_t)mh * 64 * 1024, 1024, 16,
              (const unsigned short*)0, 0, 0, p.wihF[2], 1024,
              (const unsigned short*)0, 0, g * 64, As, Bs, acc);
    float* gd = p.gi[2][tg & 1];
#pragma unroll
    for (int ni = 0; ni < 2; ++ni)
#pragma unroll
      for (int mi = 0; mi < 2; ++mi)
#pragma unroll
        for (int rr = 0; rr < 4; ++rr) {
          int row = mh * 64 + wr * 32 + mi * 16 + quad * 4 + rr;
          int colg = g * 64 + wc * 32 + ni * 16 + l16;
          gd[(size_t)row * 6144 + colg] = acc[mi][ni][rr];
        }
  }
}

__global__ void cast_kernel(const float* __restrict__ src,
                            unsigned short* __restrict__ dst, int n) {
  int i = blockIdx.x * 256 + threadIdx.x;
  if (i < n) dst[i] = f2b(src[i]);
}

extern "C" void kernel_launch(void* const* d_in, const int* in_sizes, int n_in,
                              void* d_out, int out_size, void* d_ws,
                              size_t ws_size, hipStream_t stream) {
  const int B = 128, T = 128, I = 512;
  const int Hs[3] = {512, 1024, 2048};

  const float* x = (const float*)d_in[0];
  const float* mask = (const float*)d_in[1];
  const float* Wih[3] = {(const float*)d_in[2], (const float*)d_in[5],
                         (const float*)d_in[8]};
  const float* Whh[3] = {(const float*)d_in[3], (const float*)d_in[6],
                         (const float*)d_in[9]};
  const float* bias[3] = {(const float*)d_in[4], (const float*)d_in[7],
                          (const float*)d_in[10]};

  char* ws = (char*)d_ws;
  size_t off = 0;
  auto alloc = [&](size_t bytes) -> void* {
    void* p = ws + off;
    off = (off + bytes + 255) & ~(size_t)255;
    return p;
  };

  unsigned short* xb = (unsigned short*)alloc((size_t)B * T * I * 2);
  unsigned short *wihb[3], *whhb[3];
  for (int l = 0; l < 3; ++l) {
    int inl = (l == 0) ? I : Hs[l - 1];
    wihb[l] = (unsigned short*)alloc((size_t)3 * Hs[l] * inl * 2);
    whhb[l] = (unsigned short*)alloc((size_t)3 * Hs[l] * Hs[l] * 2);
  }
  size_t hstart = off;
  DiagP p;
  for (int l = 0; l < 3; ++l)
    for (int sl = 0; sl < 2; ++sl)
      p.hf[l][sl] = (float*)alloc((size_t)B * Hs[l] * 4);
  for (int l = 0; l < 3; ++l)
    for (int sl = 0; sl < 2; ++sl)
      p.hb[l][sl] = (unsigned short*)alloc((size_t)B * Hs[l] * 2);
  size_t hend = off;
  for (int l = 0; l < 3; ++l) p.zb[l] = (float*)alloc((size_t)B * Hs[l] * 4);
  for (int l = 0; l < 3; ++l)
    p.rh[l] = (unsigned short*)alloc((size_t)B * Hs[l] * 2);
  p.gi[0][0] = p.gi[0][1] = (float*)0;
  for (int l = 1; l < 3; ++l)
    for (int sl = 0; sl < 2; ++sl)
      p.gi[l][sl] = (float*)alloc((size_t)B * 3 * Hs[l] * 4);
  (void)ws_size;

  p.xb = xb;
  p.wihzr0 = wihb[0];
  p.wihn0 = wihb[0] + (size_t)2 * Hs[0] * I;
  for (int l = 0; l < 3; ++l) {
    p.wihF[l] = wihb[l];
    p.whhzr[l] = whhb[l];
    p.whhn[l] = whhb[l] + (size_t)2 * Hs[l] * Hs[l];
    p.bias[l] = bias[l];
  }
  p.mask = mask;
  p.out = (float*)d_out;

  auto cast = [&](const float* s, unsigned short* d, int n) {
    cast_kernel<<<(n + 255) / 256, 256, 0, stream>>>(s, d, n);
  };
  cast(x, xb, B * T * I);
  for (int l = 0; l < 3; ++l) {
    int inl = (l == 0) ? I : Hs[l - 1];
    cast(Wih[l], wihb[l], 3 * Hs[l] * inl);
    cast(Whh[l], whhb[l], 3 * Hs[l] * Hs[l]);
  }
  hipMemsetAsync(ws + hstart, 0, hend - hstart, stream);
  hipMemsetAsync(d_out, 0, (size_t)out_size * 4, stream);

  // ---- diagonal scan: tick u covers layer l at t = u - 2l ----
  // gi1(tg=u-1) rides in zr(u); gi2(tg=u-3) rides in n(u).
  for (int u = 0; u < 132; ++u) {
    diag_zr<<<320, 256, 0, stream>>>(p, u);
    diag_n<<<304, 256, 0, stream>>>(p, u);
  }
}

// Round 9
// 5418.109 us; speedup vs baseline: 1.5491x; 1.5491x over previous
//
#include <hip/hip_runtime.h>
#include <hip/hip_bf16.h>

// ---------------------------------------------------------------------------
// 3-layer original-paper GRU, B=128, T=128, I=512, H={512,1024,2048}.
// Round 14: R12 (proven 6862us) with 4 waves/block (256 thr) -- 12 waves/CU.
//  - R13 (BK=64): +22% regression. Chunk count = K/BK is the critical-path
//    currency; per-chunk fixed cost ~0.5us dominates bytes. BK=128 final.
//  - R12's win = co-residency (6 waves/CU). This round doubles waves/CU at
//    IDENTICAL geometry: M=64 x N=32 x BK=128 tiles, 48KB LDS, 3 blk/CU,
//    but 256 thr: wave w owns rows w*16..w*16+15 (1 A-frag x 2 B-frags x
//    2 MFMA per ks). Staging 6 LLDS16/thread (was 12).
//  - Schedule/roles/grids/numerics byte-identical to R12: tick u = layer l
//    at t=u-2l; zr launch (640) = zr-gates + gi1; n launch (608) = n-gates
//    + gi2; mh halves same-XCD; coherence via kernel boundaries only.
// ---------------------------------------------------------------------------

typedef __attribute__((ext_vector_type(8))) short s16x8;
typedef __attribute__((ext_vector_type(4))) float f32x4;

#define LLDS16(g, s)                                                          \
  __builtin_amdgcn_global_load_lds(                                           \
      (const __attribute__((address_space(1))) void*)(g),                     \
      (__attribute__((address_space(3))) void*)(s), 16, 0, 0)

__device__ __forceinline__ unsigned short f2b(float f) {
  unsigned int u = __float_as_uint(f);
  unsigned int r = (u + 0x7FFFu + ((u >> 16) & 1u)) >> 16;
  return (unsigned short)r;
}
__device__ __forceinline__ float sigmoidf_(float x) {
  return 1.0f / (1.0f + __expf(-x));
}
__device__ __forceinline__ float tanhf_(float x) {
  x = fminf(fmaxf(x, -15.0f), 15.0f);
  float e = __expf(-2.0f * x);
  return (1.0f - e) / (1.0f + e);
}

struct DiagP {
  const unsigned short* xb;            // [B,T,I] bf16
  const unsigned short* wihzr0;        // [2*512, 512]
  const unsigned short* wihn0;         // [512, 512]
  const unsigned short* wihF[3];       // full [3H, inl] (l=1,2 used)
  const unsigned short* whhzr[3];      // [2H, H]
  const unsigned short* whhn[3];       // [H, H]
  const float* bias[3];                // [3H]
  float* hf[3][2];                     // f32 h, 2 slots (tick parity)
  unsigned short* hb[3][2];            // bf16 h, 2 slots
  float* zb[3];                        // [B,H] f32
  unsigned short* rh[3];               // [B,H] bf16
  float* gi[3][2];                     // [B,3H] f32, 2 slots (t parity)
  const float* mask;                   // [B,T]
  float* out;                          // [B,3584]
};

// ---- staging (256 thr): A tile 64x128 (16KB), B tile 32x128 (8KB) ---------
// LDS row r at r*256B; 16B granule cg holds source col-group cg^(r&15).
__device__ __forceinline__ void stageA(const unsigned short* __restrict__ g,
                                       size_t ld, int k0, unsigned short* lds) {
  const int tid = threadIdx.x;
#pragma unroll
  for (int j = 0; j < 4; ++j) {
    int idx = j * 256 + tid;          // 0..1023 granules
    int r = idx >> 4;                 // 0..63
    int cg = (idx & 15) ^ (r & 15);
    LLDS16(g + (size_t)r * ld + k0 + cg * 8, lds + idx * 8);
  }
}
__device__ __forceinline__ void stageB(const unsigned short* __restrict__ g,
                                       size_t ld, int rowbase, int k0,
                                       unsigned short* lds) {
  const int tid = threadIdx.x;
#pragma unroll
  for (int j = 0; j < 2; ++j) {
    int idx = j * 256 + tid;          // 0..511 granules
    int r = idx >> 4;                 // 0..31
    int cg = (idx & 15) ^ (r & 15);
    LLDS16(g + (size_t)(rowbase + r) * ld + k0 + cg * 8, lds + idx * 8);
  }
}

// ---- one BK=128 chunk: wave w computes rows w*16+[0,16), cols [0,32) ------
// Per ks (k-32 slice): 1 A-frag read, 2 B-frag reads, 2 MFMA.
__device__ __forceinline__ void cchunk(const unsigned short* Ab,
                                       const unsigned short* Bb,
                                       f32x4 acc[2]) {
  const int tid = threadIdx.x;
  const int wave = tid >> 6, lane = tid & 63;
  const int quad = lane >> 4, l16 = lane & 15;
  const int ar = wave * 16 + l16;
#pragma unroll
  for (int ks = 0; ks < 4; ++ks) {
    int kg = ks * 4 + quad;
    s16x8 av = *(const s16x8*)(Ab + (size_t)ar * 128 + ((kg ^ (ar & 15)) * 8));
    s16x8 bv[2];
#pragma unroll
    for (int ni = 0; ni < 2; ++ni) {
      int br = ni * 16 + l16;
      bv[ni] =
          *(const s16x8*)(Bb + (size_t)br * 128 + ((kg ^ (br & 15)) * 8));
    }
#pragma unroll
    for (int ni = 0; ni < 2; ++ni)
      acc[ni] = __builtin_amdgcn_mfma_f32_16x16x32_bf16(av, bv[ni], acc[ni],
                                                        0, 0, 0);
  }
}

// acc += A1@B1^T (c1 chunks) + A2@B2^T (c2 chunks); B rows at rowbase.
// Proven 2-buffer engine: per-chunk __syncthreads drain; exposed latency
// hidden by the 11 other waves (2 blocks x 4 + own 3) on the CU.
__device__ __forceinline__ void gemm_diag(
    const unsigned short* __restrict__ A1, size_t ldA1, int c1,
    const unsigned short* __restrict__ A2, size_t ldA2, int c2,
    const unsigned short* __restrict__ B1, size_t ldB1,
    const unsigned short* __restrict__ B2, size_t ldB2, int rowbase,
    unsigned short* As, unsigned short* Bs, f32x4 acc[2]) {
  const int total = c1 + c2;
  auto issue = [&](int c, int buf) {
    unsigned short* a = As + buf * 8192;
    unsigned short* b = Bs + buf * 4096;
    if (c < c1) {
      stageA(A1, ldA1, c << 7, a);
      stageB(B1, ldB1, rowbase, c << 7, b);
    } else {
      int k0 = (c - c1) << 7;
      stageA(A2, ldA2, k0, a);
      stageB(B2, ldB2, rowbase, k0, b);
    }
  };
  issue(0, 0);
#pragma unroll 1
  for (int c = 0; c < total; ++c) {
    __syncthreads();  // drains vmcnt: chunk c resident; WAR-protects buffers
    if (c + 1 < total) issue(c + 1, (c + 1) & 1);
    cchunk(As + (c & 1) * 8192, Bs + (c & 1) * 4096, acc);
  }
}

// ---- zr launch: zr-gates + gi1. Grid 640 = 2*(224+96). -------------------
// role<224: zr(l,nt): l0 nt 0..31, l1 0..63, l2 0..127. role>=224: gi1 g.
__global__ __launch_bounds__(256) void diag_zr(DiagP p, int u) {
  __shared__ unsigned short As[2 * 8192], Bs[2 * 4096];
  const int blk = blockIdx.x;
  const int mh = (blk >= 320) ? 1 : 0;
  const int role = blk - 320 * mh;
  const int tid = threadIdx.x, wave = tid >> 6, lane = tid & 63;
  const int quad = lane >> 4, l16 = lane & 15;
  const int oldS = (u + 1) & 1;

  if (role < 224) {
    const int l = (role < 32) ? 0 : ((role < 96) ? 1 : 2);
    const int nt = role - ((l == 0) ? 0 : ((l == 1) ? 32 : 96));
    const int t = u - 2 * l;
    if (t < 0 || t >= 128) return;
    const int H = 512 << l;

    f32x4 acc[2] = {};
    if (l == 0) {
      gemm_diag(p.xb + (size_t)t * 512 + (size_t)mh * 64 * 65536, 65536, 4,
                p.hb[0][oldS] + (size_t)mh * 64 * 512, 512, 4, p.wihzr0, 512,
                p.whhzr[0], 512, nt * 32, As, Bs, acc);
    } else {
      gemm_diag(p.hb[l][oldS] + (size_t)mh * 64 * H, (size_t)H, H >> 7,
                (const unsigned short*)0, 0, 0, p.whhzr[l], (size_t)H,
                (const unsigned short*)0, 0, nt * 32, As, Bs, acc);
    }

    const float* hfo = p.hf[l][oldS];
    const float* gil = (l == 0) ? (const float*)0 : p.gi[l][t & 1];
#pragma unroll
    for (int ni = 0; ni < 2; ++ni) {
      const int colg = nt * 32 + ni * 16 + l16;
      const float bv = p.bias[l][colg];
      const bool isz = colg < H;  // uniform per block (32 | H)
      const int j = isz ? colg : colg - H;
#pragma unroll
      for (int r = 0; r < 4; ++r) {
        const int row = mh * 64 + wave * 16 + quad * 4 + r;
        float v = acc[ni][r] + bv;
        if (l) v += gil[(size_t)row * 3 * H + colg];
        float s = sigmoidf_(v);
        if (isz)
          p.zb[l][(size_t)row * H + j] = s;
        else
          p.rh[l][(size_t)row * H + j] = f2b(s * hfo[(size_t)row * H + j]);
      }
    }
  } else {
    // gi1: gi(1, tg=u-1) = h0(tg) @ WihF[1]^T (raw). Consumed zr(1,tg) @u+1.
    const int g = role - 224;  // 0..95
    const int tg = u - 1;
    if (tg < 0 || tg >= 128) return;
    f32x4 acc[2] = {};
    gemm_diag(p.hb[0][oldS] + (size_t)mh * 64 * 512, 512, 4,
              (const unsigned short*)0, 0, 0, p.wihF[1], 512,
              (const unsigned short*)0, 0, g * 32, As, Bs, acc);
    float* gd = p.gi[1][tg & 1];
#pragma unroll
    for (int ni = 0; ni < 2; ++ni)
#pragma unroll
      for (int rr = 0; rr < 4; ++rr) {
        int row = mh * 64 + wave * 16 + quad * 4 + rr;
        int colg = g * 32 + ni * 16 + l16;
        gd[(size_t)row * 3072 + colg] = acc[ni][rr];
      }
  }
}

// ---- n launch: n-gates + gi2. Grid 608 = 2*(112+192). --------------------
__global__ __launch_bounds__(256) void diag_n(DiagP p, int u) {
  __shared__ unsigned short As[2 * 8192], Bs[2 * 4096];
  const int blk = blockIdx.x;
  const int mh = (blk >= 304) ? 1 : 0;
  const int role = blk - 304 * mh;
  const int tid = threadIdx.x, wave = tid >> 6, lane = tid & 63;
  const int quad = lane >> 4, l16 = lane & 15;
  const int oldS = (u + 1) & 1, newS = u & 1;

  if (role < 112) {
    const int l = (role < 16) ? 0 : ((role < 48) ? 1 : 2);
    const int nt = role - ((l == 0) ? 0 : ((l == 1) ? 16 : 48));
    const int t = u - 2 * l;
    if (t < 0 || t >= 128) return;
    const int H = 512 << l;
    const int outoff = (l == 0) ? 0 : ((l == 1) ? 512 : 1536);

    f32x4 acc[2] = {};
    if (l == 0) {
      gemm_diag(p.xb + (size_t)t * 512 + (size_t)mh * 64 * 65536, 65536, 4,
                p.rh[0] + (size_t)mh * 64 * 512, 512, 4, p.wihn0, 512,
                p.whhn[0], 512, nt * 32, As, Bs, acc);
    } else {
      gemm_diag(p.rh[l] + (size_t)mh * 64 * H, (size_t)H, H >> 7,
                (const unsigned short*)0, 0, 0, p.whhn[l], (size_t)H,
                (const unsigned short*)0, 0, nt * 32, As, Bs, acc);
    }

    const float* hfo = p.hf[l][oldS];
    float* hfn = p.hf[l][newS];
    unsigned short* hbn = p.hb[l][newS];
    const float* gil =
        (l == 0) ? (const float*)0 : (p.gi[l][t & 1] + 2 * H);  // n chunk
#pragma unroll
    for (int ni = 0; ni < 2; ++ni) {
      const int colg = nt * 32 + ni * 16 + l16;
      const float bv = p.bias[l][2 * H + colg];
#pragma unroll
      for (int r = 0; r < 4; ++r) {
        const int row = mh * 64 + wave * 16 + quad * 4 + r;
        float v = acc[ni][r] + bv;
        if (l) v += gil[(size_t)row * 3 * H + colg];
        float nv = tanhf_(v);
        size_t idx = (size_t)row * H + colg;
        float z = p.zb[l][idx];
        float hn = (1.0f - z) * nv + z * hfo[idx];
        hfn[idx] = hn;
        hbn[idx] = f2b(hn);
        p.out[(size_t)row * 3584 + outoff + colg] +=
            p.mask[row * 128 + t] * hn;
      }
    }
  } else {
    // gi2: gi(2, tg=u-3) = h1(tg) @ WihF[2]^T (raw). Consumed zr(2,tg) @u+1.
    const int g = role - 112;  // 0..191
    const int tg = u - 3;
    if (tg < 0 || tg >= 128) return;
    f32x4 acc[2] = {};
    gemm_diag(p.hb[1][oldS] + (size_t)mh * 64 * 1024, 1024, 8,
              (const unsigned short*)0, 0, 0, p.wihF[2], 1024,
              (const unsigned short*)0, 0, g * 32, As, Bs, acc);
    float* gd = p.gi[2][tg & 1];
#pragma unroll
    for (int ni = 0; ni < 2; ++ni)
#pragma unroll
      for (int rr = 0; rr < 4; ++rr) {
        int row = mh * 64 + wave * 16 + quad * 4 + rr;
        int colg = g * 32 + ni * 16 + l16;
        gd[(size_t)row * 6144 + colg] = acc[ni][rr];
      }
  }
}

__global__ void cast_kernel(const float* __restrict__ src,
                            unsigned short* __restrict__ dst, int n) {
  int i = blockIdx.x * 256 + threadIdx.x;
  if (i < n) dst[i] = f2b(src[i]);
}

extern "C" void kernel_launch(void* const* d_in, const int* in_sizes, int n_in,
                              void* d_out, int out_size, void* d_ws,
                              size_t ws_size, hipStream_t stream) {
  const int B = 128, T = 128, I = 512;
  const int Hs[3] = {512, 1024, 2048};

  const float* x = (const float*)d_in[0];
  const float* mask = (const float*)d_in[1];
  const float* Wih[3] = {(const float*)d_in[2], (const float*)d_in[5],
                         (const float*)d_in[8]};
  const float* Whh[3] = {(const float*)d_in[3], (const float*)d_in[6],
                         (const float*)d_in[9]};
  const float* bias[3] = {(const float*)d_in[4], (const float*)d_in[7],
                          (const float*)d_in[10]};

  char* ws = (char*)d_ws;
  size_t off = 0;
  auto alloc = [&](size_t bytes) -> void* {
    void* p = ws + off;
    off = (off + bytes + 255) & ~(size_t)255;
    return p;
  };

  unsigned short* xb = (unsigned short*)alloc((size_t)B * T * I * 2);
  unsigned short *wihb[3], *whhb[3];
  for (int l = 0; l < 3; ++l) {
    int inl = (l == 0) ? I : Hs[l - 1];
    wihb[l] = (unsigned short*)alloc((size_t)3 * Hs[l] * inl * 2);
    whhb[l] = (unsigned short*)alloc((size_t)3 * Hs[l] * Hs[l] * 2);
  }
  size_t hstart = off;
  DiagP p;
  for (int l = 0; l < 3; ++l)
    for (int sl = 0; sl < 2; ++sl)
      p.hf[l][sl] = (float*)alloc((size_t)B * Hs[l] * 4);
  for (int l = 0; l < 3; ++l)
    for (int sl = 0; sl < 2; ++sl)
      p.hb[l][sl] = (unsigned short*)alloc((size_t)B * Hs[l] * 2);
  size_t hend = off;
  for (int l = 0; l < 3; ++l) p.zb[l] = (float*)alloc((size_t)B * Hs[l] * 4);
  for (int l = 0; l < 3; ++l)
    p.rh[l] = (unsigned short*)alloc((size_t)B * Hs[l] * 2);
  p.gi[0][0] = p.gi[0][1] = (float*)0;
  for (int l = 1; l < 3; ++l)
    for (int sl = 0; sl < 2; ++sl)
      p.gi[l][sl] = (float*)alloc((size_t)B * 3 * Hs[l] * 4);
  (void)ws_size;

  p.xb = xb;
  p.wihzr0 = wihb[0];
  p.wihn0 = wihb[0] + (size_t)2 * Hs[0] * I;
  for (int l = 0; l < 3; ++l) {
    p.wihF[l] = wihb[l];
    p.whhzr[l] = whhb[l];
    p.whhn[l] = whhb[l] + (size_t)2 * Hs[l] * Hs[l];
    p.bias[l] = bias[l];
  }
  p.mask = mask;
  p.out = (float*)d_out;

  auto cast = [&](const float* s, unsigned short* d, int n) {
    cast_kernel<<<(n + 255) / 256, 256, 0, stream>>>(s, d, n);
  };
  cast(x, xb, B * T * I);
  for (int l = 0; l < 3; ++l) {
    int inl = (l == 0) ? I : Hs[l - 1];
    cast(Wih[l], wihb[l], 3 * Hs[l] * inl);
    cast(Whh[l], whhb[l], 3 * Hs[l] * Hs[l]);
  }
  hipMemsetAsync(ws + hstart, 0, hend - hstart, stream);
  hipMemsetAsync(d_out, 0, (size_t)out_size * 4, stream);

  // ---- diagonal scan: tick u covers layer l at t = u - 2l ----
  // gi1(tg=u-1) rides in zr(u); gi2(tg=u-3) rides in n(u).
  for (int u = 0; u < 132; ++u) {
    diag_zr<<<640, 256, 0, stream>>>(p, u);
    diag_n<<<608, 256, 0, stream>>>(p, u);
  }
}

// Round 10
// 4796.541 us; speedup vs baseline: 1.7498x; 1.1296x over previous
//
#include <hip/hip_runtime.h>
#include <hip/hip_bf16.h>

// ---------------------------------------------------------------------------
// 3-layer original-paper GRU, B=128, T=128, I=512, H={512,1024,2048}.
// Round 15: R14 (proven 5418us) with 8 waves/block (512 thr) -> 24 waves/CU.
//  - Ladder: 6 waves/CU = 52us tick (R12), 12 = 41us (R14). Per-chunk cost
//    is a latency/occupancy term; waves/CU is the lever that keeps paying.
//  - Same geometry: M=64 x N=32 x BK=128 tiles, 48KB LDS, 3 blk/CU; now
//    wave (wr,wc) owns a 16x16 frag: 1 A-read + 1 B-read + 1 MFMA per ks.
//    __launch_bounds__(512,6) caps VGPR at 85 to guarantee 6 waves/SIMD.
//  - Schedule/roles/grids/numerics byte-identical to R14: tick u = layer l
//    at t=u-2l; zr launch (640) = zr-gates + gi1; n launch (608) = n-gates
//    + gi2; mh halves same-XCD; coherence via kernel boundaries only.
// ---------------------------------------------------------------------------

typedef __attribute__((ext_vector_type(8))) short s16x8;
typedef __attribute__((ext_vector_type(4))) float f32x4;

#define LLDS16(g, s)                                                          \
  __builtin_amdgcn_global_load_lds(                                           \
      (const __attribute__((address_space(1))) void*)(g),                     \
      (__attribute__((address_space(3))) void*)(s), 16, 0, 0)

__device__ __forceinline__ unsigned short f2b(float f) {
  unsigned int u = __float_as_uint(f);
  unsigned int r = (u + 0x7FFFu + ((u >> 16) & 1u)) >> 16;
  return (unsigned short)r;
}
__device__ __forceinline__ float sigmoidf_(float x) {
  return 1.0f / (1.0f + __expf(-x));
}
__device__ __forceinline__ float tanhf_(float x) {
  x = fminf(fmaxf(x, -15.0f), 15.0f);
  float e = __expf(-2.0f * x);
  return (1.0f - e) / (1.0f + e);
}

struct DiagP {
  const unsigned short* xb;            // [B,T,I] bf16
  const unsigned short* wihzr0;        // [2*512, 512]
  const unsigned short* wihn0;         // [512, 512]
  const unsigned short* wihF[3];       // full [3H, inl] (l=1,2 used)
  const unsigned short* whhzr[3];      // [2H, H]
  const unsigned short* whhn[3];       // [H, H]
  const float* bias[3];                // [3H]
  float* hf[3][2];                     // f32 h, 2 slots (tick parity)
  unsigned short* hb[3][2];            // bf16 h, 2 slots
  float* zb[3];                        // [B,H] f32
  unsigned short* rh[3];               // [B,H] bf16
  float* gi[3][2];                     // [B,3H] f32, 2 slots (t parity)
  const float* mask;                   // [B,T]
  float* out;                          // [B,3584]
};

// ---- staging (512 thr): A tile 64x128 (16KB), B tile 32x128 (8KB) ---------
// LDS row r at r*256B; 16B granule cg holds source col-group cg^(r&15).
__device__ __forceinline__ void stageA(const unsigned short* __restrict__ g,
                                       size_t ld, int k0, unsigned short* lds) {
  const int tid = threadIdx.x;
#pragma unroll
  for (int j = 0; j < 2; ++j) {
    int idx = j * 512 + tid;          // 0..1023 granules
    int r = idx >> 4;                 // 0..63
    int cg = (idx & 15) ^ (r & 15);
    LLDS16(g + (size_t)r * ld + k0 + cg * 8, lds + idx * 8);
  }
}
__device__ __forceinline__ void stageB(const unsigned short* __restrict__ g,
                                       size_t ld, int rowbase, int k0,
                                       unsigned short* lds) {
  const int tid = threadIdx.x;
  int idx = tid;                      // 0..511 granules
  int r = idx >> 4;                   // 0..31
  int cg = (idx & 15) ^ (r & 15);
  LLDS16(g + (size_t)(rowbase + r) * ld + k0 + cg * 8, lds + idx * 8);
}

// ---- one BK=128 chunk: wave (wr=wave>>1, wc=wave&1) computes rows
// wr*16+[0,16), cols wc*16+[0,16): per ks 1 A-read + 1 B-read + 1 MFMA.
__device__ __forceinline__ void cchunk(const unsigned short* Ab,
                                       const unsigned short* Bb,
                                       f32x4& acc) {
  const int tid = threadIdx.x;
  const int wave = tid >> 6, lane = tid & 63;
  const int wr = wave >> 1, wc = wave & 1, quad = lane >> 4, l16 = lane & 15;
  const int ar = wr * 16 + l16;
  const int br = wc * 16 + l16;
#pragma unroll
  for (int ks = 0; ks < 4; ++ks) {
    int kg = ks * 4 + quad;
    s16x8 av = *(const s16x8*)(Ab + (size_t)ar * 128 + ((kg ^ (ar & 15)) * 8));
    s16x8 bv = *(const s16x8*)(Bb + (size_t)br * 128 + ((kg ^ (br & 15)) * 8));
    acc = __builtin_amdgcn_mfma_f32_16x16x32_bf16(av, bv, acc, 0, 0, 0);
  }
}

// acc += A1@B1^T (c1 chunks) + A2@B2^T (c2 chunks); B rows at rowbase.
// Proven 2-buffer engine: per-chunk __syncthreads drain; exposed latency
// hidden by the ~23 other waves on the CU.
__device__ __forceinline__ void gemm_diag(
    const unsigned short* __restrict__ A1, size_t ldA1, int c1,
    const unsigned short* __restrict__ A2, size_t ldA2, int c2,
    const unsigned short* __restrict__ B1, size_t ldB1,
    const unsigned short* __restrict__ B2, size_t ldB2, int rowbase,
    unsigned short* As, unsigned short* Bs, f32x4& acc) {
  const int total = c1 + c2;
  auto issue = [&](int c, int buf) {
    unsigned short* a = As + buf * 8192;
    unsigned short* b = Bs + buf * 4096;
    if (c < c1) {
      stageA(A1, ldA1, c << 7, a);
      stageB(B1, ldB1, rowbase, c << 7, b);
    } else {
      int k0 = (c - c1) << 7;
      stageA(A2, ldA2, k0, a);
      stageB(B2, ldB2, rowbase, k0, b);
    }
  };
  issue(0, 0);
#pragma unroll 1
  for (int c = 0; c < total; ++c) {
    __syncthreads();  // drains vmcnt: chunk c resident; WAR-protects buffers
    if (c + 1 < total) issue(c + 1, (c + 1) & 1);
    cchunk(As + (c & 1) * 8192, Bs + (c & 1) * 4096, acc);
  }
}

// ---- zr launch: zr-gates + gi1. Grid 640 = 2*(224+96). -------------------
// role<224: zr(l,nt): l0 nt 0..31, l1 0..63, l2 0..127. role>=224: gi1 g.
__global__ __launch_bounds__(512, 6) void diag_zr(DiagP p, int u) {
  __shared__ unsigned short As[2 * 8192], Bs[2 * 4096];
  const int blk = blockIdx.x;
  const int mh = (blk >= 320) ? 1 : 0;
  const int role = blk - 320 * mh;
  const int tid = threadIdx.x, wave = tid >> 6, lane = tid & 63;
  const int wr = wave >> 1, wc = wave & 1, quad = lane >> 4, l16 = lane & 15;
  const int oldS = (u + 1) & 1;

  if (role < 224) {
    const int l = (role < 32) ? 0 : ((role < 96) ? 1 : 2);
    const int nt = role - ((l == 0) ? 0 : ((l == 1) ? 32 : 96));
    const int t = u - 2 * l;
    if (t < 0 || t >= 128) return;
    const int H = 512 << l;

    f32x4 acc = {};
    if (l == 0) {
      gemm_diag(p.xb + (size_t)t * 512 + (size_t)mh * 64 * 65536, 65536, 4,
                p.hb[0][oldS] + (size_t)mh * 64 * 512, 512, 4, p.wihzr0, 512,
                p.whhzr[0], 512, nt * 32, As, Bs, acc);
    } else {
      gemm_diag(p.hb[l][oldS] + (size_t)mh * 64 * H, (size_t)H, H >> 7,
                (const unsigned short*)0, 0, 0, p.whhzr[l], (size_t)H,
                (const unsigned short*)0, 0, nt * 32, As, Bs, acc);
    }

    const float* hfo = p.hf[l][oldS];
    const float* gil = (l == 0) ? (const float*)0 : p.gi[l][t & 1];
    const int colg = nt * 32 + wc * 16 + l16;
    const float bv = p.bias[l][colg];
    const bool isz = colg < H;  // uniform per block (32 | H)
    const int j = isz ? colg : colg - H;
#pragma unroll
    for (int r = 0; r < 4; ++r) {
      const int row = mh * 64 + wr * 16 + quad * 4 + r;
      float v = acc[r] + bv;
      if (l) v += gil[(size_t)row * 3 * H + colg];
      float s = sigmoidf_(v);
      if (isz)
        p.zb[l][(size_t)row * H + j] = s;
      else
        p.rh[l][(size_t)row * H + j] = f2b(s * hfo[(size_t)row * H + j]);
    }
  } else {
    // gi1: gi(1, tg=u-1) = h0(tg) @ WihF[1]^T (raw). Consumed zr(1,tg) @u+1.
    const int g = role - 224;  // 0..95
    const int tg = u - 1;
    if (tg < 0 || tg >= 128) return;
    f32x4 acc = {};
    gemm_diag(p.hb[0][oldS] + (size_t)mh * 64 * 512, 512, 4,
              (const unsigned short*)0, 0, 0, p.wihF[1], 512,
              (const unsigned short*)0, 0, g * 32, As, Bs, acc);
    float* gd = p.gi[1][tg & 1];
    const int colg = g * 32 + wc * 16 + l16;
#pragma unroll
    for (int rr = 0; rr < 4; ++rr) {
      int row = mh * 64 + wr * 16 + quad * 4 + rr;
      gd[(size_t)row * 3072 + colg] = acc[rr];
    }
  }
}

// ---- n launch: n-gates + gi2. Grid 608 = 2*(112+192). --------------------
__global__ __launch_bounds__(512, 6) void diag_n(DiagP p, int u) {
  __shared__ unsigned short As[2 * 8192], Bs[2 * 4096];
  const int blk = blockIdx.x;
  const int mh = (blk >= 304) ? 1 : 0;
  const int role = blk - 304 * mh;
  const int tid = threadIdx.x, wave = tid >> 6, lane = tid & 63;
  const int wr = wave >> 1, wc = wave & 1, quad = lane >> 4, l16 = lane & 15;
  const int oldS = (u + 1) & 1, newS = u & 1;

  if (role < 112) {
    const int l = (role < 16) ? 0 : ((role < 48) ? 1 : 2);
    const int nt = role - ((l == 0) ? 0 : ((l == 1) ? 16 : 48));
    const int t = u - 2 * l;
    if (t < 0 || t >= 128) return;
    const int H = 512 << l;
    const int outoff = (l == 0) ? 0 : ((l == 1) ? 512 : 1536);

    f32x4 acc = {};
    if (l == 0) {
      gemm_diag(p.xb + (size_t)t * 512 + (size_t)mh * 64 * 65536, 65536, 4,
                p.rh[0] + (size_t)mh * 64 * 512, 512, 4, p.wihn0, 512,
                p.whhn[0], 512, nt * 32, As, Bs, acc);
    } else {
      gemm_diag(p.rh[l] + (size_t)mh * 64 * H, (size_t)H, H >> 7,
                (const unsigned short*)0, 0, 0, p.whhn[l], (size_t)H,
                (const unsigned short*)0, 0, nt * 32, As, Bs, acc);
    }

    const float* hfo = p.hf[l][oldS];
    float* hfn = p.hf[l][newS];
    unsigned short* hbn = p.hb[l][newS];
    const float* gil =
        (l == 0) ? (const float*)0 : (p.gi[l][t & 1] + 2 * H);  // n chunk
    const int colg = nt * 32 + wc * 16 + l16;
    const float bv = p.bias[l][2 * H + colg];
#pragma unroll
    for (int r = 0; r < 4; ++r) {
      const int row = mh * 64 + wr * 16 + quad * 4 + r;
      float v = acc[r] + bv;
      if (l) v += gil[(size_t)row * 3 * H + colg];
      float nv = tanhf_(v);
      size_t idx = (size_t)row * H + colg;
      float z = p.zb[l][idx];
      float hn = (1.0f - z) * nv + z * hfo[idx];
      hfn[idx] = hn;
      hbn[idx] = f2b(hn);
      p.out[(size_t)row * 3584 + outoff + colg] += p.mask[row * 128 + t] * hn;
    }
  } else {
    // gi2: gi(2, tg=u-3) = h1(tg) @ WihF[2]^T (raw). Consumed zr(2,tg) @u+1.
    const int g = role - 112;  // 0..191
    const int tg = u - 3;
    if (tg < 0 || tg >= 128) return;
    f32x4 acc = {};
    gemm_diag(p.hb[1][oldS] + (size_t)mh * 64 * 1024, 1024, 8,
              (const unsigned short*)0, 0, 0, p.wihF[2], 1024,
              (const unsigned short*)0, 0, g * 32, As, Bs, acc);
    float* gd = p.gi[2][tg & 1];
    const int colg = g * 32 + wc * 16 + l16;
#pragma unroll
    for (int rr = 0; rr < 4; ++rr) {
      int row = mh * 64 + wr * 16 + quad * 4 + rr;
      gd[(size_t)row * 6144 + colg] = acc[rr];
    }
  }
}

__global__ void cast_kernel(const float* __restrict__ src,
                            unsigned short* __restrict__ dst, int n) {
  int i = blockIdx.x * 256 + threadIdx.x;
  if (i < n) dst[i] = f2b(src[i]);
}

extern "C" void kernel_launch(void* const* d_in, const int* in_sizes, int n_in,
                              void* d_out, int out_size, void* d_ws,
                              size_t ws_size, hipStream_t stream) {
  const int B = 128, T = 128, I = 512;
  const int Hs[3] = {512, 1024, 2048};

  const float* x = (const float*)d_in[0];
  const float* mask = (const float*)d_in[1];
  const float* Wih[3] = {(const float*)d_in[2], (const float*)d_in[5],
                         (const float*)d_in[8]};
  const float* Whh[3] = {(const float*)d_in[3], (const float*)d_in[6],
                         (const float*)d_in[9]};
  const float* bias[3] = {(const float*)d_in[4], (const float*)d_in[7],
                          (const float*)d_in[10]};

  char* ws = (char*)d_ws;
  size_t off = 0;
  auto alloc = [&](size_t bytes) -> void* {
    void* p = ws + off;
    off = (off + bytes + 255) & ~(size_t)255;
    return p;
  };

  unsigned short* xb = (unsigned short*)alloc((size_t)B * T * I * 2);
  unsigned short *wihb[3], *whhb[3];
  for (int l = 0; l < 3; ++l) {
    int inl = (l == 0) ? I : Hs[l - 1];
    wihb[l] = (unsigned short*)alloc((size_t)3 * Hs[l] * inl * 2);
    whhb[l] = (unsigned short*)alloc((size_t)3 * Hs[l] * Hs[l] * 2);
  }
  size_t hstart = off;
  DiagP p;
  for (int l = 0; l < 3; ++l)
    for (int sl = 0; sl < 2; ++sl)
      p.hf[l][sl] = (float*)alloc((size_t)B * Hs[l] * 4);
  for (int l = 0; l < 3; ++l)
    for (int sl = 0; sl < 2; ++sl)
      p.hb[l][sl] = (unsigned short*)alloc((size_t)B * Hs[l] * 2);
  size_t hend = off;
  for (int l = 0; l < 3; ++l) p.zb[l] = (float*)alloc((size_t)B * Hs[l] * 4);
  for (int l = 0; l < 3; ++l)
    p.rh[l] = (unsigned short*)alloc((size_t)B * Hs[l] * 2);
  p.gi[0][0] = p.gi[0][1] = (float*)0;
  for (int l = 1; l < 3; ++l)
    for (int sl = 0; sl < 2; ++sl)
      p.gi[l][sl] = (float*)alloc((size_t)B * 3 * Hs[l] * 4);
  (void)ws_size;

  p.xb = xb;
  p.wihzr0 = wihb[0];
  p.wihn0 = wihb[0] + (size_t)2 * Hs[0] * I;
  for (int l = 0; l < 3; ++l) {
    p.wihF[l] = wihb[l];
    p.whhzr[l] = whhb[l];
    p.whhn[l] = whhb[l] + (size_t)2 * Hs[l] * Hs[l];
    p.bias[l] = bias[l];
  }
  p.mask = mask;
  p.out = (float*)d_out;

  auto cast = [&](const float* s, unsigned short* d, int n) {
    cast_kernel<<<(n + 255) / 256, 256, 0, stream>>>(s, d, n);
  };
  cast(x, xb, B * T * I);
  for (int l = 0; l < 3; ++l) {
    int inl = (l == 0) ? I : Hs[l - 1];
    cast(Wih[l], wihb[l], 3 * Hs[l] * inl);
    cast(Whh[l], whhb[l], 3 * Hs[l] * Hs[l]);
  }
  hipMemsetAsync(ws + hstart, 0, hend - hstart, stream);
  hipMemsetAsync(d_out, 0, (size_t)out_size * 4, stream);

  // ---- diagonal scan: tick u covers layer l at t = u - 2l ----
  // gi1(tg=u-1) rides in zr(u); gi2(tg=u-3) rides in n(u).
  for (int u = 0; u < 132; ++u) {
    diag_zr<<<640, 512, 0, stream>>>(p, u);
    diag_n<<<608, 512, 0, stream>>>(p, u);
  }
}